// Round 11
// baseline (188.895 us; speedup 1.0000x reference)
//
#include <hip/hip_runtime.h>
#include <math.h>

// ---------------------------------------------------------------------------
// EntRNN R11: R10 with (a) 64m x 64n x 2mat wave tiles -> LDS reads/kk2 drop
// 9->6 b128 (B-frag reads halved), (b) scan_mid folded into final_k (3
// kernels total). K-loop otherwise identical to R10 (K-step 16, 48 KiB LDS,
// 3 blocks/CU). Stores (h_local, P) f16x2; final_k folds carries + streams.
// B=8, T=4096, D=256.
// ---------------------------------------------------------------------------

typedef _Float16 f16x8 __attribute__((ext_vector_type(8)));
typedef float f32x4 __attribute__((ext_vector_type(4)));
typedef float f32x16 __attribute__((ext_vector_type(16)));
typedef unsigned int u32x4 __attribute__((ext_vector_type(4)));

constexpr int B_ = 8, T_ = 4096, D_ = 256, K_ = 256;
constexpr int M_ = B_ * T_;          // 32768 rows
constexpr int CHUNK = 64;            // rows per gemm block == scan chunk
constexpr int NCH = T_ / CHUNK;      // 64 chunks per sequence
constexpr int NBLK = M_ / CHUNK;     // 512 gemm blocks
constexpr int SLICE_EL = 8192;       // W slice stride: 1024 chunks * 8 f16

struct alignas(4) XF { _Float16 x, f; };
struct alignas(4) HP2 { _Float16 h, p; };
union UHP { unsigned int u; HP2 hp; XF xf; };

__device__ __forceinline__ float fexp2(float a) { return __builtin_amdgcn_exp2f(a); }
__device__ __forceinline__ float frcp(float a) { return __builtin_amdgcn_rcpf(a); }
constexpr float L2E = 1.4426950408889634f;

__device__ __forceinline__ float fast_sigmoid(float z) {
  return frcp(1.f + fexp2(-z * L2E));
}
__device__ __forceinline__ float fast_tanh(float z) {
  const float t = fexp2(-2.f * L2E * fabsf(z));
  return copysignf((1.f - t) * frcp(1.f + t), z);
}

// ---- K0: repack W fp32 -> f16. Chunk id t = kk2*1024 + (mat*2+kc)*256 + n,
// chunk = W[n][kk2*16 + kc*8 .. +8). 16384 chunks of 8 f16.
__global__ __launch_bounds__(256) void wconv(const float* __restrict__ Win,
                                             const float* __restrict__ Wf,
                                             _Float16* __restrict__ Wh2) {
  const int t = blockIdx.x * 256 + threadIdx.x;
  const int n = t & 255;
  const int kc = (t >> 8) & 1;
  const int mat = (t >> 9) & 1;
  const int kk2 = t >> 10;
  const float* s = (mat ? Wf : Win) + (size_t)n * K_ + kk2 * 16 + kc * 8;
  f32x4 a = *(const f32x4*)s;
  f32x4 b = *(const f32x4*)(s + 4);
  f16x8 o;
  o[0] = (_Float16)a[0]; o[1] = (_Float16)a[1];
  o[2] = (_Float16)a[2]; o[3] = (_Float16)a[3];
  o[4] = (_Float16)b[0]; o[5] = (_Float16)b[1];
  o[6] = (_Float16)b[2]; o[7] = (_Float16)b[3];
  *(f16x8*)(Wh2 + (size_t)t * 8) = o;
}

// ---- K1: GEMM + activations + local scan -> HP ----------------------------
// 512 blocks x 256 thr, 48 KiB LDS -> 3 blocks/CU. Wave w: all 64 rows,
// cols [w*64, w*64+64) of BOTH mats. acc[mat][mt][nt] = 2*2*2*16 = 128.
__global__ __launch_bounds__(256, 3) void gemm_hp(
    const float* __restrict__ A, const _Float16* __restrict__ Wh2,
    const float* __restrict__ bin, const float* __restrict__ bfv,
    const float* __restrict__ mask, unsigned int* __restrict__ HPout,
    float* __restrict__ Ap, float* __restrict__ Hp) {
  __shared__ __align__(16) char smem[49152];
  char* ldsA = smem;            // 32 KiB: [m(64)][swz(32)] 16B, swz = kcg^(m&31)
  char* ldsW = smem + 32768;    // 16 KiB slice: [(mat*2+kc)*256 + n] 16B

  const int tid = threadIdx.x;
  const int w = tid >> 6, lane = tid & 63;
  const int nl = lane & 31, kh = lane >> 5;
  const int g = blockIdx.x;
  const int row0 = g * CHUNK;

  f32x16 acc[2][2][2];   // [mat][mt(row half)][nt(32-col group)]
#pragma unroll
  for (int mat = 0; mat < 2; ++mat)
#pragma unroll
    for (int mt = 0; mt < 2; ++mt)
#pragma unroll
      for (int nt = 0; nt < 2; ++nt) acc[mat][mt][nt] = (f32x16)(0.f);

  // ---- stage ALL of A (64 x 256) fp32->f16, xor-swizzled (as R10) ----
  {
    const int am = tid >> 2;
    const int ak4 = (tid & 3) * 8;
    const float* agp = A + (size_t)(row0 + am) * K_ + ak4 * 8;
#pragma unroll
    for (int j = 0; j < 8; ++j) {
      const int kcg = ak4 + j;
      f32x4 lo = *(const f32x4*)(agp + j * 8);
      f32x4 hi = *(const f32x4*)(agp + j * 8 + 4);
      f16x8 t;
      t[0] = (_Float16)lo[0]; t[1] = (_Float16)lo[1];
      t[2] = (_Float16)lo[2]; t[3] = (_Float16)lo[3];
      t[4] = (_Float16)hi[0]; t[5] = (_Float16)hi[1];
      t[6] = (_Float16)hi[2]; t[7] = (_Float16)hi[3];
      *(f16x8*)(ldsA + am * 512 + ((kcg ^ (am & 31)) << 4)) = t;
    }
  }
  __syncthreads();

  // ---- prologue: W slice kk2=0 into regs (4 x b128) ----
  f16x8 wreg[4];
#pragma unroll
  for (int j = 0; j < 4; ++j)
    wreg[j] = *(const f16x8*)(Wh2 + (size_t)(j * 256 + tid) * 8);

  // ---- K-loop: 16 slices of K=16 (R10 pattern) ----
  for (int kk2 = 0; kk2 < 16; ++kk2) {
#pragma unroll
    for (int j = 0; j < 4; ++j)
      *(f16x8*)(ldsW + (size_t)(j * 256 + tid) * 16) = wreg[j];
    if (kk2 < 15) {
#pragma unroll
      for (int j = 0; j < 4; ++j)
        wreg[j] = *(const f16x8*)(Wh2 + (size_t)(kk2 + 1) * SLICE_EL +
                                  (size_t)(j * 256 + tid) * 8);
    }
    __syncthreads();
    f16x8 afr[2];
#pragma unroll
    for (int mt = 0; mt < 2; ++mt) {
      const int ml = mt * 32 + nl;
      const int kcg = kk2 * 2 + kh;
      afr[mt] = *(const f16x8*)(ldsA + ml * 512 + ((kcg ^ (ml & 31)) << 4));
    }
#pragma unroll
    for (int mat = 0; mat < 2; ++mat)
#pragma unroll
      for (int nt = 0; nt < 2; ++nt) {
        const int n = w * 64 + nt * 32 + nl;
        f16x8 bfr = *(const f16x8*)(ldsW + (size_t)((mat * 2 + kh) * 256 + n) * 16);
#pragma unroll
        for (int mt = 0; mt < 2; ++mt)
          acc[mat][mt][nt] = __builtin_amdgcn_mfma_f32_32x32x16_f16(
              afr[mt], bfr, acc[mat][mt][nt], 0, 0, 0);
      }
    __syncthreads();
  }

  // ---- epilogue: two 32-row phases (mt = p) in 32 KiB LDS ----
  float bx[2], bf[2];
#pragma unroll
  for (int nt = 0; nt < 2; ++nt) {
    const int col = w * 64 + nt * 32 + nl;
    bx[nt] = bin[col];
    bf[nt] = bfv[col];
  }
  float madd[2][16];
#pragma unroll
  for (int mt = 0; mt < 2; ++mt)
#pragma unroll
    for (int reg = 0; reg < 16; ++reg) {
      const int rl = mt * 32 + (reg & 3) + 8 * (reg >> 2) + 4 * kh;
      madd[mt][reg] = 10000.f * mask[row0 + rl];
    }

  const int d = tid;
  float hrun = 0.f, Prun = 1.f;
#pragma unroll
  for (int p = 0; p < 2; ++p) {
    // all waves unpack their mt=p half (rows p*32 .. p*32+32)
#pragma unroll
    for (int nt = 0; nt < 2; ++nt) {
      const int col = w * 64 + nt * 32 + nl;
#pragma unroll
      for (int reg = 0; reg < 16; ++reg) {
        const int rloc = (reg & 3) + 8 * (reg >> 2) + 4 * kh;  // 0..31
        const float zx = acc[0][p][nt][reg] + bx[nt];
        const float zf = acc[1][p][nt][reg] + bf[nt] + madd[p][reg];
        XF v;
        v.x = (_Float16)fast_tanh(zx);
        v.f = (_Float16)fast_sigmoid(zf);
        *(XF*)(smem + ((size_t)rloc * D_ + col) * 4) = v;
      }
    }
    __syncthreads();
    // scan 32 timesteps, write back packed (h_local, P) in place
#pragma unroll 8
    for (int t = 0; t < 32; ++t) {
      char* slot = smem + ((size_t)t * D_ + d) * 4;
      const XF v = *(const XF*)slot;
      const float f = (float)v.f;
      const float a = 1.f - f;
      hrun = f * (float)v.x + a * hrun;
      Prun *= a;
      HP2 o;
      o.h = (_Float16)hrun;
      o.p = (_Float16)Prun;
      *(HP2*)slot = o;
    }
    __syncthreads();
    // bulk-coalesced b128 store of this 32-row phase (32 KiB)
#pragma unroll
    for (int j = 0; j < 8; ++j) {
      const int c = j * 256 + tid;            // 16B chunk id in [0,2048)
      u32x4 vv = *(const u32x4*)(smem + (size_t)c * 16);
      *(u32x4*)(HPout + (size_t)g * 16384 + (size_t)p * 8192 + (size_t)c * 4) = vv;
    }
    __syncthreads();
  }

  Ap[(size_t)g * D_ + d] = Prun;
  Hp[(size_t)g * D_ + d] = hrun;
}

// ---- K2: fold predecessor summaries + elementwise h = h_local + P*h0 ------
__global__ __launch_bounds__(256) void final_k(const unsigned int* __restrict__ HP,
                                               const float* __restrict__ Ap,
                                               const float* __restrict__ Hp,
                                               float* __restrict__ out) {
  const int g = blockIdx.x;
  const int b = g >> 6, c = g & 63;
  const int lane = threadIdx.x & 63, wv = threadIdx.x >> 6;
  const int d0 = lane * 4;

  // fold carries for this chunk: h0 = scan of (Ap,Hp)[b*64 .. b*64+c)
  f32x4 h0 = (f32x4){0.f, 0.f, 0.f, 0.f};
  const size_t s0 = ((size_t)(b * NCH)) * D_ + d0;
#pragma unroll 4
  for (int j = 0; j < c; ++j) {
    const f32x4 ap = *(const f32x4*)(Ap + s0 + (size_t)j * D_);
    const f32x4 hp = *(const f32x4*)(Hp + s0 + (size_t)j * D_);
#pragma unroll
    for (int i = 0; i < 4; ++i) h0[i] = hp[i] + ap[i] * h0[i];
  }

#pragma unroll 4
  for (int tt = 0; tt < 16; ++tt) {
    const int t = wv * 16 + tt;
    const size_t idx = ((size_t)g * CHUNK + t) * D_ + d0;
    u32x4 u = *(const u32x4*)(HP + idx);
    f32x4 o;
#pragma unroll
    for (int i = 0; i < 4; ++i) {
      UHP q; q.u = u[i];
      o[i] = (float)q.hp.h + (float)q.hp.p * h0[i];
    }
    *(f32x4*)(out + idx) = o;
  }
}

// ---------------------------------------------------------------------------
extern "C" void kernel_launch(void* const* d_in, const int* in_sizes, int n_in,
                              void* d_out, int out_size, void* d_ws, size_t ws_size,
                              hipStream_t stream) {
  const float* inputs = (const float*)d_in[0];
  const float* mask   = (const float*)d_in[1];
  const float* W_in   = (const float*)d_in[2];
  const float* b_in   = (const float*)d_in[3];
  const float* W_f    = (const float*)d_in[4];
  const float* b_f    = (const float*)d_in[5];
  float* out = (float*)d_out;
  char* ws = (char*)d_ws;

  constexpr size_t HPSZ = (size_t)M_ * D_ * 4;                    // 32 MiB
  constexpr size_t WSZ  = (size_t)2 * 256 * 256 * 2;              // 256 KiB
  constexpr size_t SUM  = (size_t)NBLK * D_ * sizeof(float);      // 512 KiB

  unsigned int* HPb = (unsigned int*)ws;
  _Float16* Wh2 = (_Float16*)(ws + HPSZ);
  float* Ap = (float*)(ws + HPSZ + WSZ);
  float* Hp = (float*)(ws + HPSZ + WSZ + SUM);

  wconv<<<64, 256, 0, stream>>>(W_in, W_f, Wh2);
  gemm_hp<<<NBLK, 256, 0, stream>>>(inputs, Wh2, b_in, b_f, mask, HPb, Ap, Hp);
  final_k<<<NBLK, 256, 0, stream>>>(HPb, Ap, Hp, out);
}

// Round 12
// 130.691 us; speedup vs baseline: 1.4454x; 1.4454x over previous
//
#include <hip/hip_runtime.h>
#include <math.h>

// ---------------------------------------------------------------------------
// EntRNN R12: R10's gemm_hp verbatim (R11's re-tile spilled acc -> 250 MB
// scratch traffic; reverted) + R11's safe merge of scan_mid into final_k.
// Pipeline: wconv (W fp32->f16 k-major repack) | gemm_hp (R6-style K-loop,
// K-step 16, 48 KiB LDS, 3 blocks/CU; epilogue scans 2x32 rows, stores
// packed (h_local,P) f16x2) | final_k (fold carries + elementwise stream).
// B=8, T=4096, D=256.
// ---------------------------------------------------------------------------

typedef _Float16 f16x8 __attribute__((ext_vector_type(8)));
typedef float f32x4 __attribute__((ext_vector_type(4)));
typedef float f32x16 __attribute__((ext_vector_type(16)));
typedef unsigned int u32x4 __attribute__((ext_vector_type(4)));

constexpr int B_ = 8, T_ = 4096, D_ = 256, K_ = 256;
constexpr int M_ = B_ * T_;          // 32768 rows
constexpr int CHUNK = 64;            // rows per gemm block == scan chunk
constexpr int NCH = T_ / CHUNK;      // 64 chunks per sequence
constexpr int NBLK = M_ / CHUNK;     // 512 gemm blocks
constexpr int SLICE_EL = 8192;       // W slice stride: 1024 chunks * 8 f16

struct alignas(4) XF { _Float16 x, f; };
struct alignas(4) HP2 { _Float16 h, p; };
union UHP { unsigned int u; HP2 hp; XF xf; };

__device__ __forceinline__ float fexp2(float a) { return __builtin_amdgcn_exp2f(a); }
__device__ __forceinline__ float frcp(float a) { return __builtin_amdgcn_rcpf(a); }
constexpr float L2E = 1.4426950408889634f;

__device__ __forceinline__ float fast_sigmoid(float z) {
  return frcp(1.f + fexp2(-z * L2E));
}
__device__ __forceinline__ float fast_tanh(float z) {
  const float t = fexp2(-2.f * L2E * fabsf(z));
  return copysignf((1.f - t) * frcp(1.f + t), z);
}

// ---- K0: repack W fp32 -> f16. Chunk id t = kk2*1024 + (mat*2+kc)*256 + n,
// chunk = W[n][kk2*16 + kc*8 .. +8). 16384 chunks of 8 f16.
__global__ __launch_bounds__(256) void wconv(const float* __restrict__ Win,
                                             const float* __restrict__ Wf,
                                             _Float16* __restrict__ Wh2) {
  const int t = blockIdx.x * 256 + threadIdx.x;
  const int n = t & 255;
  const int kc = (t >> 8) & 1;
  const int mat = (t >> 9) & 1;
  const int kk2 = t >> 10;
  const float* s = (mat ? Wf : Win) + (size_t)n * K_ + kk2 * 16 + kc * 8;
  f32x4 a = *(const f32x4*)s;
  f32x4 b = *(const f32x4*)(s + 4);
  f16x8 o;
  o[0] = (_Float16)a[0]; o[1] = (_Float16)a[1];
  o[2] = (_Float16)a[2]; o[3] = (_Float16)a[3];
  o[4] = (_Float16)b[0]; o[5] = (_Float16)b[1];
  o[6] = (_Float16)b[2]; o[7] = (_Float16)b[3];
  *(f16x8*)(Wh2 + (size_t)t * 8) = o;
}

// ---- K1: GEMM (R10 verbatim) + activations + local scan -> HP -------------
// 512 blocks x 256 thr, 48 KiB LDS -> 3 blocks/CU. 4 waves: mw=w>>1 (32-row
// half), nw=w&1 (128-col half).
__global__ __launch_bounds__(256, 3) void gemm_hp(
    const float* __restrict__ A, const _Float16* __restrict__ Wh2,
    const float* __restrict__ bin, const float* __restrict__ bfv,
    const float* __restrict__ mask, unsigned int* __restrict__ HPout,
    float* __restrict__ Ap, float* __restrict__ Hp) {
  __shared__ __align__(16) char smem[49152];
  char* ldsA = smem;            // 32 KiB: [m(64)][swz(32)] 16B, swz = kcg^(m&31)
  char* ldsW = smem + 32768;    // 16 KiB slice: [(mat*2+kc)*256 + n] 16B

  const int tid = threadIdx.x;
  const int w = tid >> 6, lane = tid & 63;
  const int mw = w >> 1, nw = w & 1;
  const int nl = lane & 31, kh = lane >> 5;
  const int ml = mw * 32 + nl;
  const int g = blockIdx.x;
  const int row0 = g * CHUNK;

  f32x16 acc[2][4];
#pragma unroll
  for (int mat = 0; mat < 2; ++mat)
#pragma unroll
    for (int nt = 0; nt < 4; ++nt) acc[mat][nt] = (f32x16)(0.f);

  // ---- stage ALL of A (64 x 256) fp32->f16, xor-swizzled ----
  {
    const int am = tid >> 2;
    const int ak4 = (tid & 3) * 8;
    const float* agp = A + (size_t)(row0 + am) * K_ + ak4 * 8;
#pragma unroll
    for (int j = 0; j < 8; ++j) {
      const int kcg = ak4 + j;
      f32x4 lo = *(const f32x4*)(agp + j * 8);
      f32x4 hi = *(const f32x4*)(agp + j * 8 + 4);
      f16x8 t;
      t[0] = (_Float16)lo[0]; t[1] = (_Float16)lo[1];
      t[2] = (_Float16)lo[2]; t[3] = (_Float16)lo[3];
      t[4] = (_Float16)hi[0]; t[5] = (_Float16)hi[1];
      t[6] = (_Float16)hi[2]; t[7] = (_Float16)hi[3];
      *(f16x8*)(ldsA + am * 512 + ((kcg ^ (am & 31)) << 4)) = t;
    }
  }
  __syncthreads();

  // ---- prologue: W slice kk2=0 into regs (4 x b128) ----
  f16x8 wreg[4];
#pragma unroll
  for (int j = 0; j < 4; ++j)
    wreg[j] = *(const f16x8*)(Wh2 + (size_t)(j * 256 + tid) * 8);

  // ---- K-loop: 16 slices of K=16 ----
  for (int kk2 = 0; kk2 < 16; ++kk2) {
#pragma unroll
    for (int j = 0; j < 4; ++j)
      *(f16x8*)(ldsW + (size_t)(j * 256 + tid) * 16) = wreg[j];
    if (kk2 < 15) {
#pragma unroll
      for (int j = 0; j < 4; ++j)
        wreg[j] = *(const f16x8*)(Wh2 + (size_t)(kk2 + 1) * SLICE_EL +
                                  (size_t)(j * 256 + tid) * 8);
    }
    __syncthreads();
    f16x8 afr;
    {
      const int kcg = kk2 * 2 + kh;
      afr = *(const f16x8*)(ldsA + ml * 512 + ((kcg ^ (ml & 31)) << 4));
    }
#pragma unroll
    for (int mat = 0; mat < 2; ++mat)
#pragma unroll
      for (int nt = 0; nt < 4; ++nt) {
        const int n = nw * 128 + nt * 32 + nl;
        f16x8 bfr = *(const f16x8*)(ldsW + (size_t)((mat * 2 + kh) * 256 + n) * 16);
        acc[mat][nt] = __builtin_amdgcn_mfma_f32_32x32x16_f16(
            afr, bfr, acc[mat][nt], 0, 0, 0);
      }
    __syncthreads();
  }

  // ---- epilogue: two 32-row phases in 32 KiB LDS ----
  float bx[4], bf[4];
#pragma unroll
  for (int nt = 0; nt < 4; ++nt) {
    const int col = nw * 128 + nt * 32 + nl;
    bx[nt] = bin[col];
    bf[nt] = bfv[col];
  }
  float madd[16];
#pragma unroll
  for (int reg = 0; reg < 16; ++reg) {
    const int rl = mw * 32 + (reg & 3) + 8 * (reg >> 2) + 4 * kh;
    madd[reg] = 10000.f * mask[row0 + rl];
  }

  const int d = tid;
  float hrun = 0.f, Prun = 1.f;
#pragma unroll
  for (int p = 0; p < 2; ++p) {
    if (mw == p) {  // waves holding rows [p*32, p*32+32) unpack into LDS
#pragma unroll
      for (int nt = 0; nt < 4; ++nt) {
        const int col = nw * 128 + nt * 32 + nl;
#pragma unroll
        for (int reg = 0; reg < 16; ++reg) {
          const int rloc = (reg & 3) + 8 * (reg >> 2) + 4 * kh;  // 0..31
          const float zx = acc[0][nt][reg] + bx[nt];
          const float zf = acc[1][nt][reg] + bf[nt] + madd[reg];
          XF v;
          v.x = (_Float16)fast_tanh(zx);
          v.f = (_Float16)fast_sigmoid(zf);
          *(XF*)(smem + ((size_t)rloc * D_ + col) * 4) = v;
        }
      }
    }
    __syncthreads();
    // scan 32 timesteps, write back packed (h_local, P) in place
#pragma unroll 8
    for (int t = 0; t < 32; ++t) {
      char* slot = smem + ((size_t)t * D_ + d) * 4;
      const XF v = *(const XF*)slot;
      const float f = (float)v.f;
      const float a = 1.f - f;
      hrun = f * (float)v.x + a * hrun;
      Prun *= a;
      HP2 o;
      o.h = (_Float16)hrun;
      o.p = (_Float16)Prun;
      *(HP2*)slot = o;
    }
    __syncthreads();
    // bulk-coalesced b128 store of this 32-row phase (32 KiB)
#pragma unroll
    for (int j = 0; j < 8; ++j) {
      const int c = j * 256 + tid;            // 16B chunk id in [0,2048)
      u32x4 vv = *(const u32x4*)(smem + (size_t)c * 16);
      *(u32x4*)(HPout + (size_t)g * 16384 + (size_t)p * 8192 + (size_t)c * 4) = vv;
    }
    __syncthreads();
  }

  Ap[(size_t)g * D_ + d] = Prun;
  Hp[(size_t)g * D_ + d] = hrun;
}

// ---- K2: fold predecessor summaries + elementwise h = h_local + P*h0 ------
__global__ __launch_bounds__(256) void final_k(const unsigned int* __restrict__ HP,
                                               const float* __restrict__ Ap,
                                               const float* __restrict__ Hp,
                                               float* __restrict__ out) {
  const int g = blockIdx.x;
  const int b = g >> 6, c = g & 63;
  const int lane = threadIdx.x & 63, wv = threadIdx.x >> 6;
  const int d0 = lane * 4;

  // fold carries for this chunk: h0 = scan of (Ap,Hp)[b*64 .. b*64+c)
  f32x4 h0 = (f32x4){0.f, 0.f, 0.f, 0.f};
  const size_t s0 = ((size_t)(b * NCH)) * D_ + d0;
#pragma unroll 4
  for (int j = 0; j < c; ++j) {
    const f32x4 ap = *(const f32x4*)(Ap + s0 + (size_t)j * D_);
    const f32x4 hp = *(const f32x4*)(Hp + s0 + (size_t)j * D_);
#pragma unroll
    for (int i = 0; i < 4; ++i) h0[i] = hp[i] + ap[i] * h0[i];
  }

#pragma unroll 4
  for (int tt = 0; tt < 16; ++tt) {
    const int t = wv * 16 + tt;
    const size_t idx = ((size_t)g * CHUNK + t) * D_ + d0;
    u32x4 u = *(const u32x4*)(HP + idx);
    f32x4 o;
#pragma unroll
    for (int i = 0; i < 4; ++i) {
      UHP q; q.u = u[i];
      o[i] = (float)q.hp.h + (float)q.hp.p * h0[i];
    }
    *(f32x4*)(out + idx) = o;
  }
}

// ---------------------------------------------------------------------------
extern "C" void kernel_launch(void* const* d_in, const int* in_sizes, int n_in,
                              void* d_out, int out_size, void* d_ws, size_t ws_size,
                              hipStream_t stream) {
  const float* inputs = (const float*)d_in[0];
  const float* mask   = (const float*)d_in[1];
  const float* W_in   = (const float*)d_in[2];
  const float* b_in   = (const float*)d_in[3];
  const float* W_f    = (const float*)d_in[4];
  const float* b_f    = (const float*)d_in[5];
  float* out = (float*)d_out;
  char* ws = (char*)d_ws;

  constexpr size_t HPSZ = (size_t)M_ * D_ * 4;                    // 32 MiB
  constexpr size_t WSZ  = (size_t)2 * 256 * 256 * 2;              // 256 KiB
  constexpr size_t SUM  = (size_t)NBLK * D_ * sizeof(float);      // 512 KiB

  unsigned int* HPb = (unsigned int*)ws;
  _Float16* Wh2 = (_Float16*)(ws + HPSZ);
  float* Ap = (float*)(ws + HPSZ + WSZ);
  float* Hp = (float*)(ws + HPSZ + WSZ + SUM);

  wconv<<<64, 256, 0, stream>>>(W_in, W_f, Wh2);
  gemm_hp<<<NBLK, 256, 0, stream>>>(inputs, Wh2, b_in, b_f, mask, HPb, Ap, Hp);
  final_k<<<NBLK, 256, 0, stream>>>(HPb, Ap, Hp, out);
}